// Round 4
// baseline (123.032 us; speedup 1.0000x reference)
//
#include <hip/hip_runtime.h>
#include <math.h>

#define NBULK 62
#define SB    72   // padded LDS row stride (bf16)
#define NPSI  128
#define NBLK  130  // 2 norm + 128 psi

typedef __attribute__((ext_vector_type(8))) short bf8_t;   // 8 x bf16
typedef __attribute__((ext_vector_type(4))) float f4_t;    // 4 x fp32

#define MFMA(a, b, c) __builtin_amdgcn_mfma_f32_16x16x32_bf16((a), (b), (c), 0, 0, 0)

__device__ __forceinline__ unsigned short f2bf(float f) {
    unsigned int u = __float_as_uint(f);
    return (unsigned short)((u + 0x7FFFu + ((u >> 16) & 1u)) >> 16);
}
__device__ __forceinline__ float bf2f(unsigned short h) {
    return __uint_as_float(((unsigned int)h) << 16);
}

// ---- ws layout ----
// floats: [0]=psisum [1]=lsf [2]=lsb ; int slot [3]=completion counter
// E_fwd at float 1024, E_bwd at float 6144
// bytes:  BT (swizzled, 62*16KB) at 45056 ; MR (swizzled) at 1060864
#define WS_E_OFF   1024
#define WS_B_OFF   6144
#define WS_BT_OFF  45056
#define WS_MR_OFF  1060864

// swizzled element offset of (row n, col k) in a 128x64 bf16 tile:
//   n*64 + ((k>>3 ^ (n&7))<<3 | (k&7)) ; 8-elem group g at n*64 + ((g ^ (n&7))<<3)

extern "C" __global__ __launch_bounds__(256)
void mps_precompute(const float* __restrict__ bulkG,
                    unsigned short* __restrict__ BTg,
                    unsigned short* __restrict__ MRg,
                    float* __restrict__ wsF)
{
    __shared__ unsigned short BTl[8192];
    __shared__ unsigned short MRl[8192];
    const int s = blockIdx.x, tid = threadIdx.x;
    if (s == 0 && tid == 0) {
        wsF[0] = 0.f; wsF[1] = 0.f; wsF[2] = 0.f;
        ((int*)wsF)[3] = 0;
    }
    const float4* src = (const float4*)(bulkG + (size_t)s * 8192);
    for (int c = 0; c < 8; ++c) {
        int idx = tid + c * 256;
        float4 v = src[idx];
        int f  = idx * 4;
        int kk = f >> 7;
        int p  = (f >> 6) & 1;
        int j  = f & 63;
        unsigned short b0 = f2bf(v.x), b1 = f2bf(v.y), b2 = f2bf(v.z), b3 = f2bf(v.w);
        int n = p * 64 + kk;
        int off = n * 64 + (((j >> 3) ^ (n & 7)) << 3) + (j & 7);
        MRl[off + 0] = b0; MRl[off + 1] = b1; MRl[off + 2] = b2; MRl[off + 3] = b3;
        unsigned short bb[4] = {b0, b1, b2, b3};
        #pragma unroll
        for (int t2 = 0; t2 < 4; ++t2) {
            int n2 = p * 64 + j + t2;
            BTl[n2 * 64 + (((kk >> 3) ^ (n2 & 7)) << 3) + (kk & 7)] = bb[t2];
        }
    }
    __syncthreads();
    const uint4* bt4 = (const uint4*)BTl;
    const uint4* mr4 = (const uint4*)MRl;
    uint4* btg = (uint4*)(BTg + (size_t)s * 8192);
    uint4* mrg = (uint4*)(MRg + (size_t)s * 8192);
    for (int c = 0; c < 4; ++c) {
        int idx = tid + c * 256;
        btg[idx] = bt4[idx];
        mrg[idx] = mr4[idx];
    }
}

extern "C" __global__ __launch_bounds__(256, 1)
void mps_main(const int* __restrict__ cfgG, const float* __restrict__ leftG,
              const float* __restrict__ rightG, float* __restrict__ wsF,
              const unsigned short* __restrict__ BTg,
              const unsigned short* __restrict__ MRg,
              float* __restrict__ outG)
{
    extern __shared__ char smem[];
    unsigned short* smem16 = (unsigned short*)smem;
    const int tid  = threadIdx.x;
    const int bid  = blockIdx.x;
    const int wv   = tid >> 6;
    const int lane = tid & 63;
    const int quad = lane >> 4;
    const int ln   = lane & 15;

    if (bid >= 2) {
        // ===== psi: 64 samples/block, wave-private, NO barriers in main loop =====
        unsigned short* env  = smem16;                           // 64 x SB
        unsigned char*  selT = (unsigned char*)(env + 64 * SB);  // [col][sample]

        const int s0 = (bid - 2) * 64;
        {
            int m = tid >> 2, part = tid & 3;
            const int* row = cfgG + (size_t)(s0 + m) * 64 + part * 16;
            #pragma unroll
            for (int q = 0; q < 4; ++q) {
                int4 v = *(const int4*)(row + q * 4);
                int cb = part * 16 + q * 4;
                selT[(cb + 0) * 64 + m] = (unsigned char)v.x;
                selT[(cb + 1) * 64 + m] = (unsigned char)v.y;
                selT[(cb + 2) * 64 + m] = (unsigned char)v.z;
                selT[(cb + 3) * 64 + m] = (unsigned char)v.w;
            }
        }
        __syncthreads();   // selT ready (only barrier before epilogue)

        // per-lane constant global frag offsets
        int boff[2][4][2];
        #pragma unroll
        for (int b2 = 0; b2 < 2; ++b2)
            #pragma unroll
            for (int ct = 0; ct < 4; ++ct) {
                int row = b2 * 64 + ct * 16 + ln;
                #pragma unroll
                for (int h = 0; h < 2; ++h)
                    boff[b2][ct][h] = row * 64 + (((h * 4 + quad) ^ (ln & 7)) << 3);
            }

        bf8_t Af0, Af1;
        {
            int sel0 = selT[0 * 64 + wv * 16 + ln];
            const float* lp0 = leftG + sel0 * 64;
            bf8_t t0, t1;
            #pragma unroll
            for (int j = 0; j < 8; ++j) {
                t0[j] = (short)f2bf(lp0[quad * 8 + j]);
                t1[j] = (short)f2bf(lp0[32 + quad * 8 + j]);
            }
            Af0 = t0; Af1 = t1;
        }

        auto loadB = [&](bf8_t (&B)[2][4][2], int t) {
            const unsigned short* base = BTg + (size_t)t * 8192;
            #pragma unroll
            for (int b2 = 0; b2 < 2; ++b2)
                #pragma unroll
                for (int ct = 0; ct < 4; ++ct)
                    #pragma unroll
                    for (int h = 0; h < 2; ++h)
                        B[b2][ct][h] = *(const bf8_t*)(base + boff[b2][ct][h]);
        };
        auto psite = [&](bf8_t (&B)[2][4][2], int t) {
            f4_t acc[2][4];
            #pragma unroll
            for (int b2 = 0; b2 < 2; ++b2)
                #pragma unroll
                for (int ct = 0; ct < 4; ++ct) {
                    f4_t a = {0.f, 0.f, 0.f, 0.f};
                    a = MFMA(Af0, B[b2][ct][0], a);
                    a = MFMA(Af1, B[b2][ct][1], a);
                    acc[b2][ct] = a;
                }
            unsigned int sv = *(const unsigned int*)(selT + (t + 1) * 64 + wv * 16 + quad * 4);
            #pragma unroll
            for (int ct = 0; ct < 4; ++ct)
                #pragma unroll
                for (int r = 0; r < 4; ++r) {
                    float v = ((sv >> (8 * r)) & 1u) ? acc[1][ct][r] : acc[0][ct][r];
                    env[(wv * 16 + quad * 4 + r) * SB + ct * 16 + ln] = f2bf(v);
                }
            // same-wave DS ordering guarantees RAW on env
            Af0 = *(const bf8_t*)(env + (wv * 16 + ln) * SB + quad * 8);
            Af1 = *(const bf8_t*)(env + (wv * 16 + ln) * SB + 32 + quad * 8);
        };

        bf8_t BfA[2][4][2], BfB[2][4][2];
        loadB(BfA, 0);
        for (int tt = 0; tt < 31; ++tt) {
            loadB(BfB, 2 * tt + 1);          // prefetch odd site
            psite(BfA, 2 * tt);
            if (tt < 30) loadB(BfA, 2 * tt + 2);
            psite(BfB, 2 * tt + 1);
        }
        {   // psi = env . right[:, selL]
            int selL = selT[63 * 64 + wv * 16 + ln];
            bf8_t e0 = *(const bf8_t*)(env + (wv * 16 + ln) * SB + quad * 16);
            bf8_t e1 = *(const bf8_t*)(env + (wv * 16 + ln) * SB + quad * 16 + 8);
            float p = 0.f;
            #pragma unroll
            for (int j = 0; j < 8; ++j)
                p = fmaf(bf2f((unsigned short)e0[j]), rightG[(quad * 16 + j) * 2 + selL], p);
            #pragma unroll
            for (int j = 0; j < 8; ++j)
                p = fmaf(bf2f((unsigned short)e1[j]), rightG[(quad * 16 + 8 + j) * 2 + selL], p);
            p += __shfl_xor(p, 16);
            p += __shfl_xor(p, 32);
            float lp = logf(fmaxf(p * p, 1e-12f));
            lp += __shfl_xor(lp, 1); lp += __shfl_xor(lp, 2);
            lp += __shfl_xor(lp, 4); lp += __shfl_xor(lp, 8);
            if (lane == 0) atomicAdd(&wsF[0], lp);
        }
    } else {
        // ===== norm chain: 4 waves, M-frags from global (no vmcnt drain at barriers) =====
        unsigned short* Ebf = smem16;                    // 64 x SB
        unsigned short* St0 = Ebf + 64 * SB;
        unsigned short* St1 = St0 + 64 * SB;
        float* wred = (float*)(St1 + 64 * SB);           // [2][4]

        const bool fwd = (bid == 0);
        const unsigned short* srcbase = fwd ? BTg : MRg;
        {
            int i = tid >> 2, jq = tid & 3;
            for (int jj = 0; jj < 16; ++jj) {
                int j = jq * 16 + jj;
                float v;
                if (fwd) v = leftG[i] * leftG[j] + leftG[64 + i] * leftG[64 + j];
                else     v = rightG[i * 2] * rightG[j * 2] + rightG[i * 2 + 1] * rightG[j * 2 + 1];
                Ebf[i * SB + j] = f2bf(v);
            }
        }
        float lsum = 0.f;
        const int p   = wv >> 1;
        const int ntb = (wv & 1) * 2;
        const int mta = (wv >> 1) * 2;
        const int nta = (wv & 1) * 2;
        unsigned short* Stp = p ? St1 : St0;

        // per-lane constant global offsets
        int o1[2][2], o2[2][2][2];
        #pragma unroll
        for (int c = 0; c < 2; ++c) {
            int row = p * 64 + (ntb + c) * 16 + ln;
            #pragma unroll
            for (int h = 0; h < 2; ++h)
                o1[c][h] = row * 64 + (((h * 4 + quad) ^ (ln & 7)) << 3);
        }
        #pragma unroll
        for (int pp = 0; pp < 2; ++pp)
            #pragma unroll
            for (int mi = 0; mi < 2; ++mi) {
                int row = pp * 64 + (mta + mi) * 16 + ln;
                #pragma unroll
                for (int h = 0; h < 2; ++h)
                    o2[pp][mi][h] = row * 64 + (((h * 4 + quad) ^ (ln & 7)) << 3);
            }

        auto loadM = [&](bf8_t (&M1)[2][2], bf8_t (&M2)[2][2][2], int site) {
            const unsigned short* base = srcbase + (size_t)site * 8192;
            #pragma unroll
            for (int c = 0; c < 2; ++c)
                #pragma unroll
                for (int h = 0; h < 2; ++h)
                    M1[c][h] = *(const bf8_t*)(base + o1[c][h]);
            #pragma unroll
            for (int pp = 0; pp < 2; ++pp)
                #pragma unroll
                for (int mi = 0; mi < 2; ++mi)
                    #pragma unroll
                    for (int h = 0; h < 2; ++h)
                        M2[pp][mi][h] = *(const bf8_t*)(base + o2[pp][mi][h]);
        };
        auto nsite = [&](bf8_t (&M1)[2][2], bf8_t (&M2)[2][2][2],
                         bf8_t (&N1)[2][2], bf8_t (&N2)[2][2][2], int k, bool pf) {
            __syncthreads();   // Ebf(k-1) + wred(k-1) visible (lgkm-only drain)
            float inv = 1.f;
            if (k > 0) {
                const float* wp = wred + ((k - 1) & 1) * 4;
                float mm = fmaxf(fmaxf(wp[0], wp[1]), fmaxf(wp[2], wp[3]));
                float sc = fmaxf(mm, 1e-30f);
                inv = 1.f / sc;
                if (tid == 0) lsum += logf(sc);
            }
            if (pf) loadM(N1, N2, fwd ? (k + 1) : (61 - (k + 1)));   // prefetch next site
            // stage1: S_p = E x Op_p  (St transposed)
            {
                bf8_t Af2[4][2];
                #pragma unroll
                for (int mt = 0; mt < 4; ++mt)
                    #pragma unroll
                    for (int h = 0; h < 2; ++h)
                        Af2[mt][h] = *(const bf8_t*)(Ebf + (mt * 16 + ln) * SB + h * 32 + quad * 8);
                #pragma unroll
                for (int c = 0; c < 2; ++c) {
                    int nt = ntb + c;
                    #pragma unroll
                    for (int mt = 0; mt < 4; ++mt) {
                        f4_t a = {0.f, 0.f, 0.f, 0.f};
                        a = MFMA(Af2[mt][0], M1[c][0], a);
                        a = MFMA(Af2[mt][1], M1[c][1], a);
                        ushort4 pk;
                        pk.x = f2bf(a[0]); pk.y = f2bf(a[1]); pk.z = f2bf(a[2]); pk.w = f2bf(a[3]);
                        *(ushort4*)(Stp + (nt * 16 + ln) * SB + mt * 16 + quad * 4) = pk;
                    }
                }
            }
            __syncthreads();   // St visible
            // stage2: E' = sum_p Mside_p x S_p
            {
                bf8_t Bw[2][2][2];
                #pragma unroll
                for (int pp = 0; pp < 2; ++pp)
                    #pragma unroll
                    for (int ni = 0; ni < 2; ++ni)
                        #pragma unroll
                        for (int h = 0; h < 2; ++h)
                            Bw[pp][ni][h] = *(const bf8_t*)((pp ? St1 : St0)
                                            + ((nta + ni) * 16 + ln) * SB + h * 32 + quad * 8);
                float mx = 0.f;
                #pragma unroll
                for (int mi = 0; mi < 2; ++mi)
                    #pragma unroll
                    for (int ni = 0; ni < 2; ++ni) {
                        f4_t a = {0.f, 0.f, 0.f, 0.f};
                        #pragma unroll
                        for (int pp = 0; pp < 2; ++pp)
                            #pragma unroll
                            for (int h = 0; h < 2; ++h)
                                a = MFMA(M2[pp][mi][h], Bw[pp][ni][h], a);
                        #pragma unroll
                        for (int r = 0; r < 4; ++r) {
                            float val = a[r] * inv;
                            mx = fmaxf(mx, fabsf(val));
                            Ebf[((mta + mi) * 16 + quad * 4 + r) * SB + (nta + ni) * 16 + ln] = f2bf(val);
                        }
                    }
                #pragma unroll
                for (int off = 32; off > 0; off >>= 1)
                    mx = fmaxf(mx, __shfl_xor(mx, off));
                if (lane == 0) wred[(k & 1) * 4 + wv] = mx;
            }
        };

        bf8_t M1A[2][2], M2A[2][2][2], M1B[2][2], M2B[2][2][2];
        loadM(M1A, M2A, fwd ? 0 : 61);
        for (int kk = 0; kk < 15; ++kk) {
            nsite(M1A, M2A, M1B, M2B, 2 * kk,     true);
            nsite(M1B, M2B, M1A, M2A, 2 * kk + 1, true);
        }
        nsite(M1A, M2A, M1B, M2B, 30, false);

        __syncthreads();
        float* dst = wsF + (fwd ? WS_E_OFF : WS_B_OFF);
        for (int c = 0; c < 16; ++c) {
            int idx = tid + c * 256;
            dst[idx] = bf2f(Ebf[(idx >> 6) * SB + (idx & 63)]);
        }
        if (tid == 0) wsF[fwd ? 1 : 2] = lsum;
    }

    // ===== fused finalize: last block to finish computes the output =====
    __syncthreads();
    __threadfence();                 // release: prior global stores/atomics visible device-wide
    __syncthreads();
    int* eflag = (int*)smem;
    if (tid == 0) {
        int old = atomicAdd((int*)wsF + 3, 1);
        eflag[0] = (old == NBLK - 1) ? 1 : 0;
    }
    __syncthreads();
    if (eflag[0]) {
        __threadfence();             // acquire: invalidate caches before reading others' data
        const float4* E  = (const float4*)(wsF + WS_E_OFF);
        const float4* Bm = (const float4*)(wsF + WS_B_OFF);
        float a = 0.f;
        #pragma unroll
        for (int c = 0; c < 4; ++c) {
            int idx = tid + c * 256;
            float4 e = E[idx], b = Bm[idx];
            a += e.x * b.x + e.y * b.y + e.z * b.z + e.w * b.w;
        }
        #pragma unroll
        for (int off = 32; off > 0; off >>= 1)
            a += __shfl_down(a, off);
        float* ered = (float*)smem + 8;
        if ((tid & 63) == 0) ered[tid >> 6] = a;
        __syncthreads();
        if (tid == 0) {
            float z = fmaxf(ered[0] + ered[1] + ered[2] + ered[3], 1e-30f);
            float log_z = logf(z) + wsF[1] + wsF[2];
            outG[0] = log_z - wsF[0] * (1.0f / 8192.0f);
        }
    }
}

extern "C" void kernel_launch(void* const* d_in, const int* in_sizes, int n_in,
                              void* d_out, int out_size, void* d_ws, size_t ws_size,
                              hipStream_t stream)
{
    const int*   cfg   = (const int*)d_in[0];    // (8192, 64) int32
    const float* left  = (const float*)d_in[1];  // (2, 64)
    const float* bulk  = (const float*)d_in[2];  // (62, 64, 2, 64)
    const float* right = (const float*)d_in[3];  // (64, 2)
    float* wsF = (float*)d_ws;
    unsigned short* BTg = (unsigned short*)((char*)d_ws + WS_BT_OFF);
    unsigned short* MRg = (unsigned short*)((char*)d_ws + WS_MR_OFF);

    mps_precompute<<<dim3(62), dim3(256), 0, stream>>>(bulk, BTg, MRg, wsF);
    // blocks 0,1 = norm chains; 2..129 = psi (64 samples each); finalize fused
    mps_main<<<dim3(NBLK), dim3(256), 28672, stream>>>(cfg, left, right, wsF, BTg, MRg, (float*)d_out);
}